// Round 6
// baseline (117.226 us; speedup 1.0000x reference)
//
#include <hip/hip_runtime.h>
#include <math.h>

#define NBATCH 8
#define NL 128
#define IND 512
#define DEPN 45
#define DEPD 16
#define WCOLS 528          // IN_DIM + DEP_DIM
#define NP 1664            // extended GEMM width
#define C_P1 0
#define C_P2 512
#define C_HT 1024
#define C_D1 1536
#define C_D2 1581
#define C_PAD 1626

// ================= k_prep =================
// blocks [0,45):    Y1,Y2 (45x512), Ew[t]
// blocks [45,237):  transpose W1h/W2h/Wg -> Wt[d][m*512+o]
// blocks [237,301): hpa[row][d] = h[row][d] * wpos(row)
// blocks [301,365): zero Wt pad cols (8 d-rows each); blk 0 also fills bias_ext
__global__ __launch_bounds__(256) void k_prep(
    const float* __restrict__ h, const unsigned char* __restrict__ mask,
    const float* __restrict__ emb,
    const float* __restrict__ W1, const float* __restrict__ W2,
    const float* __restrict__ Wg,
    const float* __restrict__ b1, const float* __restrict__ b2,
    const float* __restrict__ bg,
    float* __restrict__ hpa, float* __restrict__ Wt,
    float* __restrict__ Y1, float* __restrict__ Y2, float* __restrict__ Ew,
    float* __restrict__ bias_ext) {
    int bid = blockIdx.x;
    int tid = threadIdx.x;

    if (bid < DEPN) {
        int t = bid;
        __shared__ float es[DEPD];
        __shared__ float red[4];
        if (tid < DEPD) es[tid] = emb[t * DEPD + tid];
        __syncthreads();
        float p = 0.f;
        for (int half = 0; half < 2; half++) {
            int o = tid + half * 256;
            float y1 = 0.f, y2 = 0.f;
#pragma unroll
            for (int e = 0; e < DEPD; e++) {
                y1 += es[e] * W1[o * WCOLS + IND + e];
                y2 += es[e] * W2[o * WCOLS + IND + e];
            }
            Y1[t * 512 + o] = y1;
            Y2[t * 512 + o] = y2;
            p += y1 * y2;
        }
        for (int off = 32; off; off >>= 1) p += __shfl_down(p, off, 64);
        if ((tid & 63) == 0) red[tid >> 6] = p;
        __syncthreads();
        if (tid == 0) Ew[t] = red[0] + red[1] + red[2] + red[3];
    } else if (bid < DEPN + 192) {
        int tile = bid - DEPN;
        int m = tile >> 6;
        int t = tile & 63;
        int orow = (t >> 3) * 64;
        int dcol = (t & 7) * 64;
        const float* W = (m == 0) ? W1 : (m == 1) ? W2 : Wg;
        int stride = (m == 2) ? IND : WCOLS;
        __shared__ float tl[64][65];
        int tx = tid & 63, ty = tid >> 6;
#pragma unroll
        for (int r = 0; r < 64; r += 4)
            tl[ty + r][tx] = W[(size_t)(orow + ty + r) * stride + dcol + tx];
        __syncthreads();
#pragma unroll
        for (int r = 0; r < 64; r += 4)
            Wt[(size_t)(dcol + ty + r) * NP + m * 512 + orow + tx] = tl[tx][ty + r];
    } else if (bid < DEPN + 192 + 64) {
        int blk = bid - (DEPN + 192);
        int rb = blk * 16;
        int b = rb >> 7;
        __shared__ int sflag, smin, smax;
        __shared__ float w16[16];
        if (tid == 0) { sflag = 0; smin = NL; smax = -1; }
        __syncthreads();
        const int* mi = (const int*)mask;
        if (tid < 128) {
            int v0 = mi[tid], v1 = mi[tid + 128];
            if ((unsigned)v0 > 1u || (unsigned)v1 > 1u) atomicOr(&sflag, 1);
        }
        __syncthreads();
        if (tid < 128) {
            int mval = sflag ? (int)mask[b * NL + tid] : mi[b * NL + tid];
            if (mval) { atomicMin(&smin, tid); atomicMax(&smax, tid); }
        }
        __syncthreads();
        if (tid < 16) {
            int any = (smax >= 0);
            int s = any ? smin : 0;
            int e = any ? smax : (NL - 1);
            int i = (rb & 127) + tid;
            const float invL = 1.0f / (float)NL;
            float w;
            if (i < s)      w = 1.0f - (float)(s - i) * invL;
            else if (i > e) w = 1.0f - (float)(i - e) * invL;
            else            w = 0.0f;
            int mval = sflag ? (int)mask[b * NL + i] : mi[b * NL + i];
            if (mval) w = 0.0f;
            w16[tid] = w;
        }
        __syncthreads();
        for (int idx = tid; idx < 16 * 128; idx += 256) {
            int r = idx >> 7, dc = (idx & 127) << 2;
            float4 hv = *(const float4*)&h[(size_t)(rb + r) * IND + dc];
            float wv = w16[r];
            hv.x *= wv; hv.y *= wv; hv.z *= wv; hv.w *= wv;
            *(float4*)&hpa[(size_t)(rb + r) * IND + dc] = hv;
        }
    } else {
        // ---- zero pad cols of Wt (8 d-rows per block); blk 0: bias_ext base ----
        int blk = bid - (DEPN + 192 + 64);   // 0..63
        int d0 = blk * 8;
        int r = tid >> 5, c = tid & 31;
        Wt[(size_t)(d0 + r) * NP + C_PAD + c] = 0.f;
        if (c < 6) Wt[(size_t)(d0 + r) * NP + C_PAD + 32 + c] = 0.f;
        if (blk == 0) {
            for (int i = tid; i < 512; i += 256) {
                bias_ext[C_P1 + i] = b1[i];
                bias_ext[C_P2 + i] = b2[i];
                bias_ext[C_HT + i] = bg[i];
            }
            if (tid < NP - C_PAD) bias_ext[C_PAD + tid] = 0.f;
        }
    }
}

// ================= k_prep2: Z columns + D-bias =================
__global__ __launch_bounds__(256) void k_prep2(
    const float* __restrict__ b1, const float* __restrict__ b2,
    const float* __restrict__ Y1, const float* __restrict__ Y2,
    const float* __restrict__ Ew,
    float* __restrict__ Wt, float* __restrict__ bias_ext) {
    int t = blockIdx.x;
    int m = blockIdx.y;
    int chunk = blockIdx.z;
    int tid = threadIdx.x;
    int w = tid >> 6, l = tid & 63;
    __shared__ float ys[512];
    const float* Y = (m == 0) ? Y2 : Y1;
    ys[tid] = Y[t * 512 + tid];
    ys[tid + 256] = Y[t * 512 + tid + 256];
    __syncthreads();

    int dbase = chunk * 128;
    int colD = (m == 0) ? (C_D1 + t) : (C_D2 + t);
    for (int r = w; r < 128; r += 4) {
        int d = dbase + r;
        const float* wr = Wt + (size_t)d * NP + m * 512;
        float s = 0.f;
#pragma unroll
        for (int k = 0; k < 8; k++) s += wr[l + k * 64] * ys[l + k * 64];
        for (int off = 32; off; off >>= 1) s += __shfl_down(s, off, 64);
        if (l == 0) Wt[(size_t)d * NP + colD] = s;
    }

    if (chunk == 0 && tid < 64) {
        const float* bb = (m == 0) ? b1 : b2;
        float s = 0.f;
#pragma unroll
        for (int k = 0; k < 8; k++) s += bb[tid + k * 64] * ys[tid + k * 64];
        for (int off = 32; off; off >>= 1) s += __shfl_down(s, off, 64);
        if (tid == 0) {
            if (m == 0) bias_ext[C_D1 + t] = s + Ew[t];
            else        bias_ext[C_D2 + t] = s;
        }
    }
}

// ================= k3: Pout = hpa @ Wt + bias_ext =================
// Tile 16 rows x 128 cols, 256 threads = 32 colthreads (4 cols, float4)
// x 8 rowgroups (2 rows). 8 outputs/thread -> 3328 waves (3.25/SIMD).
// Full-iteration W register prefetch (two 8-row float4 groups, ping-pong).
// 1D grid 832 = 8 XCD x 104, XCD-grouped so same-W-panel blocks share L2.
#define ACCR(A, H, W0, W1_, W2_, W3_) \
    A.x += H.x*W0.x + H.y*W1_.x + H.z*W2_.x + H.w*W3_.x; \
    A.y += H.x*W0.y + H.y*W1_.y + H.z*W2_.y + H.w*W3_.y; \
    A.z += H.x*W0.z + H.y*W1_.z + H.z*W2_.z + H.w*W3_.z; \
    A.w += H.x*W0.w + H.y*W1_.w + H.z*W2_.w + H.w*W3_.w;

#define LOADW8(P, DD, V0, V1, V2, V3, V4, V5, V6, V7) \
    V0 = *(const float4*)((P) + (size_t)((DD) + 0) * NP); \
    V1 = *(const float4*)((P) + (size_t)((DD) + 1) * NP); \
    V2 = *(const float4*)((P) + (size_t)((DD) + 2) * NP); \
    V3 = *(const float4*)((P) + (size_t)((DD) + 3) * NP); \
    V4 = *(const float4*)((P) + (size_t)((DD) + 4) * NP); \
    V5 = *(const float4*)((P) + (size_t)((DD) + 5) * NP); \
    V6 = *(const float4*)((P) + (size_t)((DD) + 6) * NP); \
    V7 = *(const float4*)((P) + (size_t)((DD) + 7) * NP);

#define FMA8(DD, V0, V1, V2, V3, V4, V5, V6, V7) \
    { \
        float4 ha0 = *(const float4*)&hs[r0][DD]; \
        float4 ha1 = *(const float4*)&hs[r0][(DD) + 4]; \
        float4 hb0 = *(const float4*)&hs[r0 + 1][DD]; \
        float4 hb1 = *(const float4*)&hs[r0 + 1][(DD) + 4]; \
        ACCR(acc0, ha0, V0, V1, V2, V3) \
        ACCR(acc0, ha1, V4, V5, V6, V7) \
        ACCR(acc1, hb0, V0, V1, V2, V3) \
        ACCR(acc1, hb1, V4, V5, V6, V7) \
    }

__global__ __launch_bounds__(256) void k3_gemm(
    const float* __restrict__ hpa, const float* __restrict__ Wt,
    const float* __restrict__ bias_ext, float* __restrict__ Pout) {
    int bid = blockIdx.x;                 // 832 = 8 * 104
    int work = (bid & 7) * 104 + (bid >> 3);
    int cb = work >> 6;                   // 0..12
    int rb = (work & 63) << 4;            // 0..1008
    int tid = threadIdx.x;
    int c = tid & 31, g = tid >> 5;       // colthread, rowgroup
    int col = cb * 128 + c * 4;
    int r0 = g * 2;

    __shared__ float hs[16][IND];         // 32 KB
    {
        const float4* src = (const float4*)(hpa + (size_t)rb * IND);
        float4* dst = (float4*)&hs[0][0];
#pragma unroll
        for (int i = 0; i < 8; i++) dst[tid + i * 256] = src[tid + i * 256];
    }
    __syncthreads();

    float4 z = {0.f, 0.f, 0.f, 0.f};
    float4 acc0 = z, acc1 = z;
    const float* Wp = Wt + col;

    float4 wa0, wa1, wa2, wa3, wa4, wa5, wa6, wa7;
    float4 wb0, wb1, wb2, wb3, wb4, wb5, wb6, wb7;
    LOADW8(Wp, 0, wa0, wa1, wa2, wa3, wa4, wa5, wa6, wa7)

    for (int d = 0; d < IND; d += 16) {
        LOADW8(Wp, d + 8, wb0, wb1, wb2, wb3, wb4, wb5, wb6, wb7)
        FMA8(d, wa0, wa1, wa2, wa3, wa4, wa5, wa6, wa7)
        int dn = (d + 16) & (IND - 1);    // last iter: dummy row 0
        LOADW8(Wp, dn, wa0, wa1, wa2, wa3, wa4, wa5, wa6, wa7)
        FMA8(d + 8, wb0, wb1, wb2, wb3, wb4, wb5, wb6, wb7)
    }

    float4 bv = *(const float4*)(bias_ext + col);
    float4 o0, o1;
    o0.x = acc0.x + bv.x; o0.y = acc0.y + bv.y; o0.z = acc0.z + bv.z; o0.w = acc0.w + bv.w;
    o1.x = acc1.x + bv.x; o1.y = acc1.y + bv.y; o1.z = acc1.z + bv.z; o1.w = acc1.w + bv.w;
    *(float4*)&Pout[(size_t)(rb + r0 + 0) * NP + col] = o0;
    *(float4*)&Pout[(size_t)(rb + r0 + 1) * NP + col] = o1;
}

// ================= k5: scores lookup + normalize + A@HT + relu =================
__global__ __launch_bounds__(128) void k5_out(
    const float* __restrict__ P, const int* __restrict__ dep,
    const float* __restrict__ bias, float* __restrict__ out) {
    int row = blockIdx.x;        // 1024
    int b = row >> 7;
    int tid = threadIdx.x;       // 128
    __shared__ float comb[DEPN];
    __shared__ float a[NL];
    __shared__ float red[2];
    __shared__ float sumv;

    const float* Prow = P + (size_t)row * NP;
    // c0 = P1 . P2
    float4 p1 = *(const float4*)(Prow + C_P1 + tid * 4);
    float4 p2 = *(const float4*)(Prow + C_P2 + tid * 4);
    float lc = p1.x * p2.x + p1.y * p2.y + p1.z * p2.z + p1.w * p2.w;
    for (int off = 32; off; off >>= 1) lc += __shfl_down(lc, off, 64);
    if ((tid & 63) == 0) red[tid >> 6] = lc;
    if (tid < DEPN) comb[tid] = Prow[C_D1 + tid] + Prow[C_D2 + tid];
    __syncthreads();

    float c0 = red[0] + red[1];
    int tt = dep[(size_t)row * NL + tid];
    float sc = (tt != 0) ? expf(c0 + comb[tt]) : 0.f;
    a[tid] = sc;
    __syncthreads();
    if (tid < 64) {
        float v = a[tid] + a[tid + 64];
        for (int off = 32; off; off >>= 1) v += __shfl_down(v, off, 64);
        if (tid == 0) sumv = v;
    }
    __syncthreads();
    float inv = 1.0f / (sumv + 1e-6f);

    // out = relu(inv * sum_j a[j]*HT[b,j,:] + bias)
    const float* htb = P + (size_t)b * NL * NP + C_HT + tid * 4;
    float sx = 0.f, sy = 0.f, sz = 0.f, sw = 0.f;
#pragma unroll 4
    for (int j = 0; j < NL; j += 2) {
        float a0 = a[j], a1 = a[j + 1];
        float4 v0 = *(const float4*)(htb + (size_t)j * NP);
        float4 v1 = *(const float4*)(htb + (size_t)(j + 1) * NP);
        sx += a0 * v0.x + a1 * v1.x;
        sy += a0 * v0.y + a1 * v1.y;
        sz += a0 * v0.z + a1 * v1.z;
        sw += a0 * v0.w + a1 * v1.w;
    }
    float4 bv = *(const float4*)&bias[tid * 4];
    float4 o;
    o.x = fmaxf(sx * inv + bv.x, 0.f);
    o.y = fmaxf(sy * inv + bv.y, 0.f);
    o.z = fmaxf(sz * inv + bv.z, 0.f);
    o.w = fmaxf(sw * inv + bv.w, 0.f);
    *(float4*)&out[(size_t)row * 512 + tid * 4] = o;
}

extern "C" void kernel_launch(void* const* d_in, const int* in_sizes, int n_in,
                              void* d_out, int out_size, void* d_ws, size_t ws_size,
                              hipStream_t stream) {
    const float* h    = (const float*)d_in[0];
    const int* dep    = (const int*)d_in[1];
    const unsigned char* mask = (const unsigned char*)d_in[2];
    const float* emb  = (const float*)d_in[3];
    const float* W1   = (const float*)d_in[4];
    const float* b1   = (const float*)d_in[5];
    const float* W2   = (const float*)d_in[6];
    const float* b2   = (const float*)d_in[7];
    const float* Wg   = (const float*)d_in[8];
    const float* bg   = (const float*)d_in[9];
    const float* bias = (const float*)d_in[10];
    float* out = (float*)d_out;

    float* ws = (float*)d_ws;
    float* hpa      = ws;                      // 524288
    float* Wt       = hpa + 524288;            // 512*1664 = 851968
    float* bias_ext = Wt + 851968;             // 1664
    float* Y1       = bias_ext + 1664;         // 23040
    float* Y2       = Y1 + 23040;              // 23040
    float* Ew       = Y2 + 23040;              // 64
    float* Pout     = Ew + 64;                 // 1024*1664 = 1703936

    k_prep<<<DEPN + 192 + 64 + 64, 256, 0, stream>>>(h, mask, emb, W1, W2, Wg,
                                                     b1, b2, bg,
                                                     hpa, Wt, Y1, Y2, Ew, bias_ext);
    dim3 g2(DEPN, 2, 4);
    k_prep2<<<g2, 256, 0, stream>>>(b1, b2, Y1, Y2, Ew, Wt, bias_ext);
    k3_gemm<<<832, 256, 0, stream>>>(hpa, Wt, bias_ext, Pout);
    k5_out<<<NBATCH * NL, 128, 0, stream>>>(Pout, dep, bias, out);
}